// Round 1
// baseline (195.066 us; speedup 1.0000x reference)
//
#include <hip/hip_runtime.h>
#include <hip/hip_bf16.h>

// Problem constants
#define VOCAB 50000
#define ED    300
#define NT    16
#define BB    64
#define SS    512

#define LOG2E 1.4426950408889634f
#define LN2   0.6931471805599453f
#define WSTR  308   // padded W-transpose stride (2-way bank aliasing = free)
#define NBLK  2048  // producer blocks (= grid size)

// ---------------------------------------------------------------------------
// DPP helpers (controls HW-verified). old = src (involutions, all lanes
// active -> old never observed).
// ---------------------------------------------------------------------------
template <int CTRL>
__device__ __forceinline__ float dppmov(float x) {
  int xi = __float_as_int(x);
  return __int_as_float(
      __builtin_amdgcn_update_dpp(xi, xi, CTRL, 0xF, 0xF, false));
}

// ---------------------------------------------------------------------------
// One CRF forward step, fused DPP matvec (HW-verified).
//   gn_j = (sum_k alpha_{j^k} * E[k]_j) * pe_j,  E[k]_j ~ exp(trans[j^k, j])
// ---------------------------------------------------------------------------
__device__ __forceinline__ float crf_step(float g, float pe, const float E[16]) {
  float gn, h, m, c, a1, a2, a3;
  asm("s_nop 1\n\t"
      "v_mov_b32_dpp %[h], %[g] row_half_mirror row_mask:0xf bank_mask:0xf\n\t"
      "v_mov_b32_dpp %[m], %[g] row_mirror row_mask:0xf bank_mask:0xf\n\t"
      "v_mul_f32 %[gn], %[g], %[e0]\n\t"
      "v_fmac_f32_dpp %[gn], %[g], %[e1] quad_perm:[1,0,3,2] row_mask:0xf bank_mask:0xf\n\t"
      "v_fmac_f32_dpp %[gn], %[g], %[e2] quad_perm:[2,3,0,1] row_mask:0xf bank_mask:0xf\n\t"
      "v_fmac_f32_dpp %[gn], %[g], %[e3] quad_perm:[3,2,1,0] row_mask:0xf bank_mask:0xf\n\t"
      "v_mov_b32_dpp %[c], %[m] row_half_mirror row_mask:0xf bank_mask:0xf\n\t"
      "v_mul_f32 %[a1], %[h], %[e7]\n\t"
      "v_fmac_f32_dpp %[a1], %[h], %[e6] quad_perm:[1,0,3,2] row_mask:0xf bank_mask:0xf\n\t"
      "v_fmac_f32_dpp %[a1], %[h], %[e5] quad_perm:[2,3,0,1] row_mask:0xf bank_mask:0xf\n\t"
      "v_fmac_f32_dpp %[a1], %[h], %[e4] quad_perm:[3,2,1,0] row_mask:0xf bank_mask:0xf\n\t"
      "v_mul_f32 %[a2], %[m], %[e15]\n\t"
      "v_fmac_f32_dpp %[a2], %[m], %[e14] quad_perm:[1,0,3,2] row_mask:0xf bank_mask:0xf\n\t"
      "v_fmac_f32_dpp %[a2], %[m], %[e13] quad_perm:[2,3,0,1] row_mask:0xf bank_mask:0xf\n\t"
      "v_fmac_f32_dpp %[a2], %[m], %[e12] quad_perm:[3,2,1,0] row_mask:0xf bank_mask:0xf\n\t"
      "v_mul_f32 %[a3], %[c], %[e8]\n\t"
      "v_fmac_f32_dpp %[a3], %[c], %[e9] quad_perm:[1,0,3,2] row_mask:0xf bank_mask:0xf\n\t"
      "v_fmac_f32_dpp %[a3], %[c], %[e10] quad_perm:[2,3,0,1] row_mask:0xf bank_mask:0xf\n\t"
      "v_fmac_f32_dpp %[a3], %[c], %[e11] quad_perm:[3,2,1,0] row_mask:0xf bank_mask:0xf\n\t"
      "v_add_f32 %[gn], %[gn], %[a1]\n\t"
      "v_add_f32 %[a2], %[a2], %[a3]\n\t"
      "v_add_f32 %[gn], %[gn], %[a2]\n\t"
      "v_mul_f32 %[gn], %[gn], %[pe]"
      : [gn] "=&v"(gn), [h] "=&v"(h), [m] "=&v"(m), [c] "=&v"(c),
        [a1] "=&v"(a1), [a2] "=&v"(a2), [a3] "=&v"(a3)
      : [g] "v"(g), [pe] "v"(pe),
        [e0] "v"(E[0]), [e1] "v"(E[1]), [e2] "v"(E[2]), [e3] "v"(E[3]),
        [e4] "v"(E[4]), [e5] "v"(E[5]), [e6] "v"(E[6]), [e7] "v"(E[7]),
        [e8] "v"(E[8]), [e9] "v"(E[9]), [e10] "v"(E[10]), [e11] "v"(E[11]),
        [e12] "v"(E[12]), [e13] "v"(E[13]), [e14] "v"(E[14]), [e15] "v"(E[15]));
  return gn;
}

// ---------------------------------------------------------------------------
// Fused kernel. All 2048 blocks: probs tile (16 rows) with NT stores, then a
// relaxed agent-scope done-count. Blocks 0..63 additionally run the CRF for
// batch b = blockIdx: probs-independent prep (lens, binary score, E) happens
// BEFORE the spin so it hides under the producer tail; the scan reads probs
// directly from cache (no LDS staging) via the existing 16-deep register
// prefetch. Consumer phase is wave0-only, no barriers (waves 1-3 exited).
// ---------------------------------------------------------------------------
__global__ __launch_bounds__(256) void fused_kernel(const int* __restrict__ text,
                                                    const int* __restrict__ tags,
                                                    const float* __restrict__ emb,
                                                    const float* __restrict__ W,
                                                    const float* __restrict__ bias,
                                                    const float* __restrict__ trans,
                                                    float* __restrict__ out_probs,
                                                    float* __restrict__ out_lens,
                                                    float* __restrict__ out_ll,
                                                    int* __restrict__ cnt) {
  __shared__ float wt[NT * WSTR];  // wt[t*WSTR + d] = W[d*16 + t]

  const int tid = threadIdx.x;
  const int lane = tid & 63, wave = tid >> 6;
  const int r = lane >> 4, t = lane & 15;
  const int row = blockIdx.x * 16 + wave * 4 + r;

  // ---- probs tile (identical structure to round-4 verified kernel) ----
  for (int e = tid; e < ED * NT; e += 256) {
    int d = e >> 4, tt = e & 15;
    wt[tt * WSTR + d] = W[e];
  }

  const int tok = text[row];
  const float4* erow = (const float4*)(emb + (size_t)tok * ED);
  float acc = bias[t];

  float4 A[8];
#pragma unroll
  for (int i = 0; i < 8; ++i) A[i] = erow[i];

  __syncthreads();

  const float4* w4 = (const float4*)(wt + t * WSTR);
#pragma unroll
  for (int c = 0; c < 75; ++c) {
    float4 e = A[c & 7];
    if (c < 67) A[c & 7] = erow[c + 8];
    float4 w = w4[c];
    acc = fmaf(e.x, w.x, acc);
    acc = fmaf(e.y, w.y, acc);
    acc = fmaf(e.z, w.z, acc);
    acc = fmaf(e.w, w.w, acc);
  }
  // NT store -> bypasses L2 to the coherent point; consumers read after inv.
  __builtin_nontemporal_store(acc, out_probs + (size_t)row * NT + t);

  __syncthreads();  // compiler drains vmcnt(0) for every wave before s_barrier
  if (tid == 0)
    __hip_atomic_fetch_add(cnt, 1, __ATOMIC_RELAXED, __HIP_MEMORY_SCOPE_AGENT);

  const int b = blockIdx.x;
  if (b >= BB || tid >= 64) return;  // consumer = wave0 of blocks 0..63

  const int j = tid & 15;

  // ---- probs-independent prep (overlaps producer tail) ----
  // lens
  const int* tx = text + b * SS;
  int cz = 0;
#pragma unroll
  for (int k = 0; k < 8; ++k) cz += (tx[tid + 64 * k] != 0) ? 1 : 0;
  for (int off = 32; off > 0; off >>= 1) cz += __shfl_xor(cz, off, 64);
  const int len = cz;
  if (tid == 0) out_lens[b] = (float)len;

  // tags + binary score (needs tags/trans only)
  const int* tg = tags + b * SS;
  int tgv[8];
  float sb = 0.f;
#pragma unroll
  for (int it = 0; it < 8; ++it) {
    const int s = tid + 64 * it;
    tgv[it] = tg[s];
    if (s >= 1 && s < len) sb += trans[tg[s - 1] * 16 + tgv[it]];
  }

  // E[k] = exp(trans[j^k, j]) * 2^-5 (scale folded back via K2)
  float E[16];
#pragma unroll
  for (int k = 0; k < 16; ++k) E[k] = __expf(trans[((j ^ k) << 4) + j]) * 0.03125f;

  // ---- spin until all 2048 producer blocks done (bounded: fails loud) ----
  {
    unsigned guard = 0;
    while (__hip_atomic_load(cnt, __ATOMIC_RELAXED, __HIP_MEMORY_SCOPE_AGENT) < NBLK) {
      __builtin_amdgcn_s_sleep(4);
      if (++guard > (1u << 22)) break;
    }
    __threadfence();  // acquire: invalidate L1/L2 before reading probs
  }

  const float* pb = out_probs + (size_t)b * SS * NT;

  // ---- scan: s = 1 .. len-1, probs read direct from cache (no LDS) ----
  float g = exp2f(pb[j] * LOG2E);  // alpha from step 0
  float K2 = 0.f;

  const int T = (len > 0) ? len - 1 : 0;
  const int nfull = T >> 4;
  const int rem = T & 15;

  float raw[16];
#pragma unroll
  for (int c = 0; c < 16; ++c) raw[c] = pb[(1 + c) * NT + j] * LOG2E;

  int s0 = 1;
  for (int blk = 0; blk < nfull; ++blk) {
#pragma unroll
    for (int c = 0; c < 16; ++c) {
      float pe = exp2f(raw[c]);
      // rows <= 512; row 512 lands in out_lens region (valid, value unused)
      raw[c] = pb[(s0 + 16 + c) * NT + j] * LOG2E;
      g = crf_step(g, pe, E);
    }
    // renorm every 4 chunks = 64 steps (exact fold into K2)
    if ((blk & 3) == 3) {
      float mx = g;
      mx = fmaxf(mx, dppmov<0xB1>(mx));
      mx = fmaxf(mx, dppmov<0x4E>(mx));
      mx = fmaxf(mx, dppmov<0x141>(mx));
      mx = fmaxf(mx, dppmov<0x140>(mx));
      float rr = 1.0f / mx;
      K2 -= __log2f(rr);
      g *= rr;
    }
    s0 += 16;
  }
  for (int c = 0; c < rem; ++c) {
    float pe = exp2f(raw[c]);
    g = crf_step(g, pe, E);
  }

  // ---- unary score (cache-warm after the scan touched every row) ----
  float su = 0.f;
#pragma unroll
  for (int it = 0; it < 8; ++it) {
    const int s = tid + 64 * it;
    if (s < len) su += pb[s * NT + tgv[it]];
  }
  float sc = su + sb;
  for (int off = 32; off > 0; off >>= 1) sc += __shfl_xor(sc, off, 64);

  // ---- final logsumexp across the 16 alphas; +5*T undoes the E scaling ----
  float x = g;
  x += dppmov<0xB1>(x);
  x += dppmov<0x4E>(x);
  x += dppmov<0x141>(x);
  x += dppmov<0x140>(x);
  float log_norm = LN2 * (K2 + 5.0f * (float)T + __log2f(x));
  if (tid == 0) out_ll[b] = sc - log_norm;
}

// ---------------------------------------------------------------------------
extern "C" void kernel_launch(void* const* d_in, const int* in_sizes, int n_in,
                              void* d_out, int out_size, void* d_ws, size_t ws_size,
                              hipStream_t stream) {
  const int* text = (const int*)d_in[0];
  const int* tags = (const int*)d_in[1];
  const float* emb = (const float*)d_in[2];
  const float* W = (const float*)d_in[3];
  const float* bias = (const float*)d_in[4];
  const float* trans = (const float*)d_in[5];

  float* out = (float*)d_out;
  float* out_probs = out;                   // 64*512*16
  float* out_lens = out + BB * SS * NT;     // 64
  float* out_ll = out + BB * SS * NT + BB;  // 64

  int* cnt = (int*)d_ws;
  hipMemsetAsync(d_ws, 0, 64, stream);  // zero the done-counter each iteration

  fused_kernel<<<NBLK, 256, 0, stream>>>(text, tags, emb, W, bias, trans,
                                         out_probs, out_lens, out_ll, cnt);
}